// Round 4
// baseline (236.028 us; speedup 1.0000x reference)
//
#include <hip/hip_runtime.h>

// LIF forward recurrence:
//   mem0 = x[0]; spike0 = (mem0 > 0.5)
//   mem_t = mem_{t-1} * 0.25 * (1 - spike_{t-1}) + x_t ; spike_t = (mem_t > 0.5)
// Output: spikes [T, B, D] float32.
//
// R1-R3 post-mortem: with VGPR-destination loads the scheduler serializes the
// load stream against stores (mixed vmcnt FIFO, ~1 load in flight) and all
// variants plateau at ~2.4 TB/s. R4: stage via __builtin_amdgcn_global_load_lds
// (no VGPR dest -> compiler CANNOT sink it). 8 timesteps/chunk staged into
// wave-private LDS slots, all 8 KiB/wave guaranteed in flight, one
// __syncthreads() per chunk as the drain. 32 KiB LDS/block keeps all 4
// resident blocks/CU -> ~128 KiB/CU in flight vs ~10 KiB needed for 6.3 TB/s.

constexpr int   T_STEPS = 32;
constexpr int   CHUNK   = 8;     // timesteps staged per barrier
constexpr float THRESH  = 0.5f;
constexpr float DECAY   = 0.25f;

typedef float v4f __attribute__((ext_vector_type(4)));

__global__ __launch_bounds__(256) void lif_fwd_kernel(
    const float4* __restrict__ x,   // [T, n4]
    float4* __restrict__ out,       // [T, n4]
    int n4)
{
    // [chunk_t][wave][lane] float4 — each wave stages/consumes only its own
    // [*][wave][*] slots (wave-private: no cross-wave hazard).
    __shared__ float4 smem[CHUNK][4][64];

    const int tid  = threadIdx.x;
    const int wave = tid >> 6;
    const int lane = tid & 63;
    const int i    = blockIdx.x * 256 + tid;

    const float4* xp = x + i;     // per-lane global base (lanes contiguous)
    float4*       op = out + i;

    float4 mem, s;

    for (int c = 0; c < T_STEPS / CHUNK; ++c) {
        const int t0 = c * CHUNK;

        // Fire-and-forget direct-to-LDS staging: 8 x 16B/lane = 8 KiB/wave
        // in flight concurrently. LDS dest is wave-uniform base + lane*16.
#pragma unroll
        for (int k = 0; k < CHUNK; ++k) {
            __builtin_amdgcn_global_load_lds(
                (const __attribute__((address_space(1))) void*)(xp + (t0 + k) * n4),
                (__attribute__((address_space(3))) void*)(&smem[k][wave][0]),
                16, 0, 0);
        }

        // Guaranteed vmcnt drain (compiler emits s_waitcnt vmcnt(0) before
        // s_barrier). Blocks stagger independently, so the memory system
        // stays fed across the drain.
        __syncthreads();

#pragma unroll
        for (int k = 0; k < CHUNK; ++k) {
            float4 v = smem[k][wave][lane];   // ds_read_b128, conflict-free
            if (t0 + k == 0) {
                mem = v;                       // mem0 = x[0]
            } else {
                mem.x = mem.x * (DECAY * (1.0f - s.x)) + v.x;
                mem.y = mem.y * (DECAY * (1.0f - s.y)) + v.y;
                mem.z = mem.z * (DECAY * (1.0f - s.z)) + v.z;
                mem.w = mem.w * (DECAY * (1.0f - s.w)) + v.w;
            }
            s.x = mem.x > THRESH ? 1.0f : 0.0f;
            s.y = mem.y > THRESH ? 1.0f : 0.0f;
            s.z = mem.z > THRESH ? 1.0f : 0.0f;
            s.w = mem.w > THRESH ? 1.0f : 0.0f;
            v4f sv = {s.x, s.y, s.z, s.w};
            __builtin_nontemporal_store(sv, (v4f*)(op + (t0 + k) * n4));
        }
        // No second barrier: smem slots are wave-private, and each wave's
        // ds_reads complete (lgkmcnt waited at use) before it can issue the
        // next chunk's global_load_lds in program order.
    }
}

extern "C" void kernel_launch(void* const* d_in, const int* in_sizes, int n_in,
                              void* d_out, int out_size, void* d_ws, size_t ws_size,
                              hipStream_t stream) {
    const float* x = (const float*)d_in[0];
    float* out = (float*)d_out;

    const int total = in_sizes[0];        // T * B * D = 33_554_432
    const int n     = total / T_STEPS;    // B * D     = 1_048_576
    const int n4    = n / 4;              // 262_144 float4 groups

    const int block = 256;
    const int grid  = (n4 + block - 1) / block;  // 1024 blocks, 4/CU

    lif_fwd_kernel<<<grid, block, 0, stream>>>(
        reinterpret_cast<const float4*>(x),
        reinterpret_cast<float4*>(out),
        n4);
}

// Round 5
// 235.181 us; speedup vs baseline: 1.0036x; 1.0036x over previous
//
#include <hip/hip_runtime.h>

// LIF forward recurrence:
//   mem0 = x[0]; spike0 = (mem0 > 0.5)
//   mem_t = mem_{t-1} * 0.25 * (1 - spike_{t-1}) + x_t ; spike_t = (mem_t > 0.5)
// Output: spikes [T, B, D] float32.
//
// R1-R4 post-mortem: 16 waves/CU with bursty chunked issue pins at ~2.4 TB/s
// regardless of mechanism (VGPR pipeline, LDS-DMA). R5 clones the 6.3 TB/s
// copy-kernel recipe: float2/thread -> 2048 blocks -> 32 waves/CU (full
// occupancy, VGPR<=64), rolled steady-state loop with register double-buffer
// so loads stay ~8 deep in the vmcnt FIFO continuously, no barriers, no LDS.
// t=0 folds into the recurrence via mem=0, s=0 (0*anything + x0 = x0).

constexpr int   T_STEPS = 32;
constexpr int   CHUNK   = 4;      // timesteps per half-buffer
constexpr float THRESH  = 0.5f;
constexpr float DECAY   = 0.25f;

__device__ __forceinline__ void lif_step(float2& mem, float2& s, float2 v) {
    mem.x = mem.x * (DECAY * (1.0f - s.x)) + v.x;
    mem.y = mem.y * (DECAY * (1.0f - s.y)) + v.y;
    s.x = mem.x > THRESH ? 1.0f : 0.0f;
    s.y = mem.y > THRESH ? 1.0f : 0.0f;
}

__global__ __launch_bounds__(256, 8) void lif_fwd_kernel(
    const float2* __restrict__ x,   // [T, n2]
    float2* __restrict__ out,       // [T, n2]
    int n2)
{
    const int i = blockIdx.x * 256 + threadIdx.x;
    if (i >= n2) return;

    const float2* xp = x + i;
    float2*       op = out + i;

    float2 A[CHUNK], B[CHUNK];

    // Prologue: chunks 0 and 1 in flight.
#pragma unroll
    for (int k = 0; k < CHUNK; ++k) A[k] = xp[k * n2];
#pragma unroll
    for (int k = 0; k < CHUNK; ++k) B[k] = xp[(CHUNK + k) * n2];

    float2 mem = {0.0f, 0.0f};
    float2 s   = {0.0f, 0.0f};

#pragma unroll 1
    for (int cc = 0; cc < T_STEPS / (2 * CHUNK); ++cc) {   // 4 iterations
        const int t0 = cc * 2 * CHUNK;

        // Consume A (t0 .. t0+3); refill A from t0+8.. (clamped; redundant
        // tail loads of plane 31 are L2-hot and keep the body branch-free).
#pragma unroll
        for (int k = 0; k < CHUNK; ++k) {
            float2 v = A[k];
            int tp = t0 + 2 * CHUNK + k;
            tp = tp < T_STEPS - 1 ? tp : T_STEPS - 1;
            A[k] = xp[tp * n2];                 // issued before this k's store
            lif_step(mem, s, v);
            op[(t0 + k) * n2] = s;
        }

        // Consume B (t0+4 .. t0+7); refill B from t0+12..
#pragma unroll
        for (int k = 0; k < CHUNK; ++k) {
            float2 v = B[k];
            int tp = t0 + 3 * CHUNK + k;
            tp = tp < T_STEPS - 1 ? tp : T_STEPS - 1;
            B[k] = xp[tp * n2];
            lif_step(mem, s, v);
            op[(t0 + CHUNK + k) * n2] = s;
        }
    }
}

extern "C" void kernel_launch(void* const* d_in, const int* in_sizes, int n_in,
                              void* d_out, int out_size, void* d_ws, size_t ws_size,
                              hipStream_t stream) {
    const float* x = (const float*)d_in[0];
    float* out = (float*)d_out;

    const int total = in_sizes[0];        // T * B * D = 33_554_432
    const int n     = total / T_STEPS;    // B * D     = 1_048_576
    const int n2    = n / 2;              // 524_288 float2 lanes

    const int block = 256;
    const int grid  = (n2 + block - 1) / block;  // 2048 blocks -> 8/CU, 32 waves/CU

    lif_fwd_kernel<<<grid, block, 0, stream>>>(
        reinterpret_cast<const float2*>(x),
        reinterpret_cast<float2*>(out),
        n2);
}